// Round 1
// baseline (4188.580 us; speedup 1.0000x reference)
//
#include <hip/hip_runtime.h>

#define NLV 8      // RVQ levels
#define KCB 1024   // codebook size
#define DM  512    // d_model
#define MT  64     // tokens per block
#define NC  128    // codebooks per chunk
#define KS  32     // k per stage
#define APAD 36    // A-tile row stride (KS + 4): 2-way max bank aliasing for ty reads
#define BPAD 132   // B-tile row stride (NC + 4): 2-way max bank aliasing for tx reads
#define NTH 256

// ---------- c2 precompute: one wave per codebook row ----------
__global__ void c2_kernel(const float* __restrict__ cbs, float* __restrict__ c2) {
    int row  = blockIdx.x;       // 0 .. NLV*KCB-1
    int lane = threadIdx.x;      // 0 .. 63
    const float4* p4 = (const float4*)(cbs + (size_t)row * DM);
    float4 a = p4[lane];
    float4 b = p4[lane + 64];
    float s = a.x*a.x + a.y*a.y + a.z*a.z + a.w*a.w
            + b.x*b.x + b.y*b.y + b.z*b.z + b.w*b.w;
    #pragma unroll
    for (int off = 32; off > 0; off >>= 1) s += __shfl_down(s, off, 64);
    if (lane == 0) c2[row] = s;
}

// ---------- one RVQ level: GEMM + argmin + residual update ----------
// rin/rout may alias (residual lives in the quantized-output buffer) -> no restrict.
__global__ __launch_bounds__(NTH, 2)
void rvq_level(const float* rin, float* rout, const float* xin,
               const float* __restrict__ cbs, const float* __restrict__ c2g,
               float* __restrict__ idxout, int lvl, int is_last) {
    __shared__ float Asd[2][MT * APAD];   // 18,432 B
    __shared__ float Bsd[2][KS * BPAD];   // 33,792 B  (k-major, transposed on stage)
    __shared__ float red_s[MT * 16];      //  4,096 B
    __shared__ int   red_i[MT * 16];      //  4,096 B
    __shared__ int   kbest[MT];           //    256 B   => 60,672 B total

    const int tid = threadIdx.x;
    const int ty  = tid >> 4;    // 0..15 : token group (4 tokens)
    const int tx  = tid & 15;    // 0..15 : codebook group (8 cbs: tx*4+j and 64+tx*4+j)
    const size_t tok0 = (size_t)blockIdx.x * MT;
    const float* cbl = cbs + (size_t)lvl * KCB * DM;
    const float* c2l = c2g + lvl * KCB;

    float bestv[4];
    int   besti[4];
    #pragma unroll
    for (int i = 0; i < 4; ++i) { bestv[i] = 3.4e38f; besti[i] = 0; }

    auto stageA = [&](int buf, int kk) {
        #pragma unroll
        for (int i = 0; i < 2; ++i) {
            int idx = tid + i * NTH;            // 0..511
            int tok = idx >> 3, f4 = idx & 7;
            float4 v = *(const float4*)&rin[(tok0 + tok) * DM + kk * KS + f4 * 4];
            *(float4*)&Asd[buf][tok * APAD + f4 * 4] = v;
        }
    };
    auto stageB = [&](int buf, int cb0, int kk) {
        #pragma unroll
        for (int i = 0; i < 4; ++i) {
            int idx = tid + i * NTH;            // 0..1023
            int cbr = idx >> 3, f4 = idx & 7;
            float4 v = *(const float4*)&cbl[(size_t)(cb0 + cbr) * DM + kk * KS + f4 * 4];
            float* bp = Bsd[buf];
            bp[(f4*4+0) * BPAD + cbr] = v.x;
            bp[(f4*4+1) * BPAD + cbr] = v.y;
            bp[(f4*4+2) * BPAD + cbr] = v.z;
            bp[(f4*4+3) * BPAD + cbr] = v.w;
        }
    };

    for (int nc = 0; nc < KCB / NC; ++nc) {
        const int cb0 = nc * NC;
        float acc[4][8];
        #pragma unroll
        for (int i = 0; i < 4; ++i)
            #pragma unroll
            for (int j = 0; j < 8; ++j) acc[i][j] = 0.f;

        __syncthreads();                 // previous readers of buf0 done
        stageA(0, 0);
        stageB(0, cb0, 0);
        __syncthreads();

        for (int kk = 0; kk < DM / KS; ++kk) {
            const int cur = kk & 1;
            if (kk + 1 < DM / KS) {      // prefetch next stage into other buffer
                stageA(cur ^ 1, kk + 1);
                stageB(cur ^ 1, cb0, kk + 1);
            }
            const float* Ac = Asd[cur];
            const float* Bc = Bsd[cur];
            #pragma unroll
            for (int kq = 0; kq < KS / 4; ++kq) {
                const int kb = kq * 4;
                float4 a0 = *(const float4*)&Ac[(ty*4+0) * APAD + kb];
                float4 a1 = *(const float4*)&Ac[(ty*4+1) * APAD + kb];
                float4 a2 = *(const float4*)&Ac[(ty*4+2) * APAD + kb];
                float4 a3 = *(const float4*)&Ac[(ty*4+3) * APAD + kb];
                #pragma unroll
                for (int kc = 0; kc < 4; ++kc) {
                    float4 b0 = *(const float4*)&Bc[(kb+kc) * BPAD + tx*4];
                    float4 b1 = *(const float4*)&Bc[(kb+kc) * BPAD + 64 + tx*4];
                    float ax0 = ((const float*)&a0)[kc];
                    float ax1 = ((const float*)&a1)[kc];
                    float ax2 = ((const float*)&a2)[kc];
                    float ax3 = ((const float*)&a3)[kc];
                    float axv[4] = {ax0, ax1, ax2, ax3};
                    #pragma unroll
                    for (int i = 0; i < 4; ++i) {
                        acc[i][0] = fmaf(axv[i], b0.x, acc[i][0]);
                        acc[i][1] = fmaf(axv[i], b0.y, acc[i][1]);
                        acc[i][2] = fmaf(axv[i], b0.z, acc[i][2]);
                        acc[i][3] = fmaf(axv[i], b0.w, acc[i][3]);
                        acc[i][4] = fmaf(axv[i], b1.x, acc[i][4]);
                        acc[i][5] = fmaf(axv[i], b1.y, acc[i][5]);
                        acc[i][6] = fmaf(axv[i], b1.z, acc[i][6]);
                        acc[i][7] = fmaf(axv[i], b1.w, acc[i][7]);
                    }
                }
            }
            __syncthreads();
        }

        // chunk epilogue: score = c2[k] - 2*dot  (r^2 term is argmin-invariant).
        // strictly-less keeps the first (lowest-k) occurrence, matching jnp.argmin.
        #pragma unroll
        for (int j = 0; j < 8; ++j) {
            int k = cb0 + (j < 4 ? (tx*4 + j) : (64 + tx*4 + (j - 4)));
            float c2v = c2l[k];
            #pragma unroll
            for (int i = 0; i < 4; ++i) {
                float s = fmaf(-2.f, acc[i][j], c2v);
                if (s < bestv[i]) { bestv[i] = s; besti[i] = k; }
            }
        }
    }

    // cross-thread argmin reduce (16 tx threads per token row)
    #pragma unroll
    for (int i = 0; i < 4; ++i) {
        red_s[(ty*4 + i) * 16 + tx] = bestv[i];
        red_i[(ty*4 + i) * 16 + tx] = besti[i];
    }
    __syncthreads();
    if (tid < MT) {
        float bv = red_s[tid * 16];
        int   bi = red_i[tid * 16];
        #pragma unroll
        for (int j = 1; j < 16; ++j) {
            float v  = red_s[tid * 16 + j];
            int   ii = red_i[tid * 16 + j];
            if (v < bv || (v == bv && ii < bi)) { bv = v; bi = ii; }
        }
        kbest[tid] = bi;
        idxout[(tok0 + tid) * NLV + lvl] = (float)bi;  // harness reads whole d_out as f32
    }
    __syncthreads();

    // residual update: r -= cb[kbest]; last level writes q = x - r_new
    for (int e = tid; e < MT * (DM / 4); e += NTH) {
        int t = e >> 7, d4 = e & 127;
        size_t goff = (tok0 + t) * DM + d4 * 4;
        float4 r = *(const float4*)&rin[goff];
        float4 c = ((const float4*)(cbl + (size_t)kbest[t] * DM))[d4];
        r.x -= c.x; r.y -= c.y; r.z -= c.z; r.w -= c.w;
        if (is_last) {
            float4 xv = *(const float4*)&xin[goff];
            float4 q = make_float4(xv.x - r.x, xv.y - r.y, xv.z - r.z, xv.w - r.w);
            *(float4*)&rout[goff] = q;
        } else {
            *(float4*)&rout[goff] = r;
        }
    }
}

extern "C" void kernel_launch(void* const* d_in, const int* in_sizes, int n_in,
                              void* d_out, int out_size, void* d_ws, size_t ws_size,
                              hipStream_t stream) {
    const float* x   = (const float*)d_in[0];   // [8,4096,512]
    const float* cbs = (const float*)d_in[1];   // [8,1024,512]
    float* qout   = (float*)d_out;                       // [8,4096,512]
    float* idxout = qout + (size_t)8 * 4096 * 512;       // [8,4096,8] as float
    float* c2     = (float*)d_ws;                        // [8,1024]

    c2_kernel<<<NLV * KCB, 64, 0, stream>>>(cbs, c2);

    const int nblocks = (8 * 4096) / MT;  // 512
    for (int l = 0; l < NLV; ++l) {
        const float* rin = (l == 0) ? x : qout;   // residual lives in qout between levels
        rvq_level<<<nblocks, NTH, 0, stream>>>(rin, qout, x, cbs, c2, idxout,
                                               l, (l == NLV - 1) ? 1 : 0);
    }
}

// Round 2
// 1265.750 us; speedup vs baseline: 3.3092x; 3.3092x over previous
//
#include <hip/hip_runtime.h>
#include <stdint.h>

#define NLV 8
#define KCB 1024
#define DM  512
#define NTOK (8*4096)

typedef _Float16 f16;
typedef f16  f16x4 __attribute__((ext_vector_type(4)));
typedef f16  f16x8 __attribute__((ext_vector_type(8)));
typedef float f32x4 __attribute__((ext_vector_type(4)));

#define SPLIT_SCALE 2048.0f
#define INV_SPLIT   (1.0f/2048.0f)

// ---------------- async global->LDS helper (16B/lane, wave-uniform LDS base) ----
typedef __attribute__((address_space(1))) const unsigned int* as1p;
typedef __attribute__((address_space(3))) unsigned int*       as3p;
__device__ __forceinline__ void gll16(const void* g, void* l) {
    __builtin_amdgcn_global_load_lds((as1p)g, (as3p)l, 16, 0, 0);
}

// ---------------- c2 precompute: one wave per codebook row ----------------
__global__ void c2_kernel(const float* __restrict__ cbs, float* __restrict__ c2) {
    int row  = blockIdx.x;
    int lane = threadIdx.x;
    const float4* p4 = (const float4*)(cbs + (size_t)row * DM);
    float4 a = p4[lane];
    float4 b = p4[lane + 64];
    float s = a.x*a.x + a.y*a.y + a.z*a.z + a.w*a.w
            + b.x*b.x + b.y*b.y + b.z*b.z + b.w*b.w;
    #pragma unroll
    for (int off = 32; off > 0; off >>= 1) s += __shfl_down(s, off, 64);
    if (lane == 0) c2[row] = s;
}

// ---------------- hi/lo split of an fp32 array (exact grid, no bounds) ---------
__global__ void split_kernel(const float* __restrict__ src,
                             f16* __restrict__ hi, f16* __restrict__ lo) {
    size_t i = (size_t)blockIdx.x * 256 + threadIdx.x;   // float4 index
    float4 v = ((const float4*)src)[i];
    f16x4 h, l;
    h.x = (f16)v.x; l.x = (f16)((v.x - (float)h.x) * SPLIT_SCALE);
    h.y = (f16)v.y; l.y = (f16)((v.y - (float)h.y) * SPLIT_SCALE);
    h.z = (f16)v.z; l.z = (f16)((v.z - (float)h.z) * SPLIT_SCALE);
    h.w = (f16)v.w; l.w = (f16)((v.w - (float)h.w) * SPLIT_SCALE);
    ((f16x4*)hi)[i] = h;
    ((f16x4*)lo)[i] = l;
}

// ---------------- main MFMA level kernel ----------------
// Block: 64 tokens, 256 threads (4 waves). Chunks of 256 codebooks (4 chunks).
// Wave tile 64(M)x64(N) = 4x4 tiles of 16x16x32_f16, split-GEMM (3 MFMA/tile/kstep).
#define MB  64
#define NCH 256
#define KS  32

__global__ __launch_bounds__(256, 2)
void rvq_mfma(const float* rin, float* rout, const float* xin,
              const float* __restrict__ cbs,
              const f16* __restrict__ Bhi, const f16* __restrict__ Blo,
              f16* __restrict__ Ahi, f16* __restrict__ Alo,
              const float* __restrict__ c2g, float* __restrict__ idxout,
              int lvl, int is_last) {
    __shared__ char smem[40960];
    f16* sAh = (f16*)smem;                 // [64][32]   4 KB
    f16* sAl = (f16*)(smem + 4096);        // [64][32]   4 KB
    f16* sBh = (f16*)(smem + 8192);        // [256][32] 16 KB
    f16* sBl = (f16*)(smem + 24576);       // [256][32] 16 KB

    const int tid  = threadIdx.x;
    const int lane = tid & 63;
    const int wid  = tid >> 6;             // wave id = N-strip within chunk
    const int tx   = lane & 15;
    const int q    = lane >> 4;
    const size_t tok0 = (size_t)blockIdx.x * MB;

    const f16*   Bh_l = Bhi + (size_t)lvl * KCB * DM;
    const f16*   Bl_l = Blo + (size_t)lvl * KCB * DM;
    const float* c2l  = c2g + lvl * KCB;
    const float* cbl  = cbs + (size_t)lvl * KCB * DM;

    float bestv[16];
    int   besti[16];
    #pragma unroll
    for (int t = 0; t < 16; ++t) { bestv[t] = 3.4e38f; besti[t] = 0; }

    // A staging source: lane covers 8 f16 at token (tid>>2), k-offset (tid&3)*8
    const size_t aRow = tok0 + (tid >> 2);
    const int    aKo  = (tid & 3) * 8;
    f16* sAh_base = sAh + 512 * wid;   // wave-uniform
    f16* sAl_base = sAl + 512 * wid;

    for (int ch = 0; ch < KCB / NCH; ++ch) {
        const int cb0 = ch * NCH;
        f32x4 ahh[4][4], axx[4][4];
        #pragma unroll
        for (int i = 0; i < 4; ++i)
            #pragma unroll
            for (int j = 0; j < 4; ++j) {
                ahh[i][j] = (f32x4)0.0f; axx[i][j] = (f32x4)0.0f;
            }

        for (int kk = 0; kk < DM / KS; ++kk) {
            const int k0 = kk * KS;
            __syncthreads();   // previous kstep's LDS consumers done
            // ---- async stage: A hi/lo (4KB each), B hi/lo (16KB each) ----
            gll16(&Ahi[aRow * DM + k0 + aKo], sAh_base);
            gll16(&Alo[aRow * DM + k0 + aKo], sAl_base);
            #pragma unroll
            for (int i = 0; i < 4; ++i) {
                int linear = i * 256 + tid;           // 0..1023
                int n  = linear >> 2;
                int ko = (linear & 3) * 8;
                size_t gsrc = (size_t)(cb0 + n) * DM + k0 + ko;
                f16* lb = sBh + 2048 * i + 512 * wid; // wave-uniform
                gll16(&Bh_l[gsrc], lb);
                gll16(&Bl_l[gsrc], (f16*)((char*)lb + 16384));
            }
            __syncthreads();   // drains vmcnt before barrier (compiler-emitted)

            // ---- fragments + MFMA ----
            f16x8 ah[4], al[4];
            #pragma unroll
            for (int i = 0; i < 4; ++i) {
                int off = (i * 16 + tx) * 32 + q * 8;
                ah[i] = *(const f16x8*)&sAh[off];
                al[i] = *(const f16x8*)&sAl[off];
            }
            #pragma unroll
            for (int j = 0; j < 4; ++j) {
                int boff = (wid * 64 + j * 16 + tx) * 32 + q * 8;
                f16x8 bh = *(const f16x8*)&sBh[boff];
                f16x8 bl = *(const f16x8*)&sBl[boff];
                #pragma unroll
                for (int i = 0; i < 4; ++i) {
                    ahh[i][j] = __builtin_amdgcn_mfma_f32_16x16x32_f16(ah[i], bh, ahh[i][j], 0, 0, 0);
                    axx[i][j] = __builtin_amdgcn_mfma_f32_16x16x32_f16(ah[i], bl, axx[i][j], 0, 0, 0);
                    axx[i][j] = __builtin_amdgcn_mfma_f32_16x16x32_f16(al[i], bh, axx[i][j], 0, 0, 0);
                }
            }
        }

        // ---- per-chunk argmin epilogue (C/D: col=lane&15, row=(lane>>4)*4+reg) ----
        #pragma unroll
        for (int j = 0; j < 4; ++j) {
            int n = cb0 + wid * 64 + j * 16 + tx;
            float c2v = c2l[n];
            #pragma unroll
            for (int i = 0; i < 4; ++i)
                #pragma unroll
                for (int r = 0; r < 4; ++r) {
                    float dot = ahh[i][j][r] + axx[i][j][r] * INV_SPLIT;
                    float s = fmaf(-2.f, dot, c2v);
                    int t = i * 4 + r;
                    if (s < bestv[t]) { bestv[t] = s; besti[t] = n; }
                }
        }
    }

    // ---- cross-lane argmin over tx (16 lanes, same q share same m rows) ----
    #pragma unroll
    for (int t = 0; t < 16; ++t) {
        float v = bestv[t]; int bi = besti[t];
        #pragma unroll
        for (int off = 1; off < 16; off <<= 1) {
            float ov = __shfl_xor(v, off, 64);
            int   oi = __shfl_xor(bi, off, 64);
            if (ov < v || (ov == v && oi < bi)) { v = ov; bi = oi; }
        }
        bestv[t] = v; besti[t] = bi;
    }

    __syncthreads();   // all frag reads done; overlay reduce arrays on smem
    float* redV  = (float*)smem;           // [4][64]
    int*   redI  = (int*)(smem + 1024);    // [4][64]
    int*   kbest = (int*)(smem + 2048);    // [64]

    if (tx == 0) {
        #pragma unroll
        for (int i = 0; i < 4; ++i)
            #pragma unroll
            for (int r = 0; r < 4; ++r) {
                int m = i * 16 + q * 4 + r;
                redV[wid * 64 + m] = bestv[i * 4 + r];
                redI[wid * 64 + m] = besti[i * 4 + r];
            }
    }
    __syncthreads();
    if (tid < MB) {
        float bv = redV[tid]; int bi = redI[tid];
        #pragma unroll
        for (int w = 1; w < 4; ++w) {
            float v  = redV[w * 64 + tid];
            int   ii = redI[w * 64 + tid];
            if (v < bv || (v == bv && ii < bi)) { bv = v; bi = ii; }
        }
        kbest[tid] = bi;
        idxout[(tok0 + tid) * NLV + lvl] = (float)bi;
    }
    __syncthreads();

    // ---- residual update (+ next level's A split), fp32-exact chain ----
    for (int it = 0; it < 32; ++it) {
        int e  = tid + it * 256;            // 64 tok x 128 float4
        int t  = e >> 7, d4 = e & 127;
        size_t go = (tok0 + t) * (size_t)DM + d4 * 4;
        float4 r = *(const float4*)&rin[go];
        float4 c = *(const float4*)&cbl[(size_t)kbest[t] * DM + d4 * 4];
        r.x -= c.x; r.y -= c.y; r.z -= c.z; r.w -= c.w;
        if (is_last) {
            float4 xv = *(const float4*)&xin[go];
            float4 qv = make_float4(xv.x - r.x, xv.y - r.y, xv.z - r.z, xv.w - r.w);
            *(float4*)&rout[go] = qv;
        } else {
            *(float4*)&rout[go] = r;
            f16x4 h, l;
            h.x = (f16)r.x; l.x = (f16)((r.x - (float)h.x) * SPLIT_SCALE);
            h.y = (f16)r.y; l.y = (f16)((r.y - (float)h.y) * SPLIT_SCALE);
            h.z = (f16)r.z; l.z = (f16)((r.z - (float)h.z) * SPLIT_SCALE);
            h.w = (f16)r.w; l.w = (f16)((r.w - (float)h.w) * SPLIT_SCALE);
            *(f16x4*)&Ahi[go] = h;
            *(f16x4*)&Alo[go] = l;
        }
    }
}

// =================== fallback (round-1 fp32 vector kernel) ===================
#define MT  64
#define NC  128
#define FKS 32
#define APAD 36
#define BPAD 132
#define NTH 256

__global__ __launch_bounds__(NTH, 2)
void rvq_level_fb(const float* rin, float* rout, const float* xin,
                  const float* __restrict__ cbs, const float* __restrict__ c2g,
                  float* __restrict__ idxout, int lvl, int is_last) {
    __shared__ float Asd[2][MT * APAD];
    __shared__ float Bsd[2][FKS * BPAD];
    __shared__ float red_s[MT * 16];
    __shared__ int   red_i[MT * 16];
    __shared__ int   kbest[MT];

    const int tid = threadIdx.x;
    const int ty  = tid >> 4;
    const int tx  = tid & 15;
    const size_t tok0 = (size_t)blockIdx.x * MT;
    const float* cbl = cbs + (size_t)lvl * KCB * DM;
    const float* c2l = c2g + lvl * KCB;

    float bestv[4]; int besti[4];
    #pragma unroll
    for (int i = 0; i < 4; ++i) { bestv[i] = 3.4e38f; besti[i] = 0; }

    auto stageA = [&](int buf, int kk) {
        #pragma unroll
        for (int i = 0; i < 2; ++i) {
            int idx = tid + i * NTH;
            int tok = idx >> 3, f4 = idx & 7;
            float4 v = *(const float4*)&rin[(tok0 + tok) * DM + kk * FKS + f4 * 4];
            *(float4*)&Asd[buf][tok * APAD + f4 * 4] = v;
        }
    };
    auto stageB = [&](int buf, int cb0, int kk) {
        #pragma unroll
        for (int i = 0; i < 4; ++i) {
            int idx = tid + i * NTH;
            int cbr = idx >> 3, f4 = idx & 7;
            float4 v = *(const float4*)&cbl[(size_t)(cb0 + cbr) * DM + kk * FKS + f4 * 4];
            float* bp = Bsd[buf];
            bp[(f4*4+0) * BPAD + cbr] = v.x;
            bp[(f4*4+1) * BPAD + cbr] = v.y;
            bp[(f4*4+2) * BPAD + cbr] = v.z;
            bp[(f4*4+3) * BPAD + cbr] = v.w;
        }
    };

    for (int nc = 0; nc < KCB / NC; ++nc) {
        const int cb0 = nc * NC;
        float acc[4][8];
        #pragma unroll
        for (int i = 0; i < 4; ++i)
            #pragma unroll
            for (int j = 0; j < 8; ++j) acc[i][j] = 0.f;

        __syncthreads();
        stageA(0, 0); stageB(0, cb0, 0);
        __syncthreads();

        for (int kk = 0; kk < DM / FKS; ++kk) {
            const int cur = kk & 1;
            if (kk + 1 < DM / FKS) { stageA(cur ^ 1, kk + 1); stageB(cur ^ 1, cb0, kk + 1); }
            const float* Ac = Asd[cur];
            const float* Bc = Bsd[cur];
            #pragma unroll
            for (int kq = 0; kq < FKS / 4; ++kq) {
                const int kb = kq * 4;
                float4 a0 = *(const float4*)&Ac[(ty*4+0) * APAD + kb];
                float4 a1 = *(const float4*)&Ac[(ty*4+1) * APAD + kb];
                float4 a2 = *(const float4*)&Ac[(ty*4+2) * APAD + kb];
                float4 a3 = *(const float4*)&Ac[(ty*4+3) * APAD + kb];
                #pragma unroll
                for (int kc = 0; kc < 4; ++kc) {
                    float4 b0 = *(const float4*)&Bc[(kb+kc) * BPAD + tx*4];
                    float4 b1 = *(const float4*)&Bc[(kb+kc) * BPAD + 64 + tx*4];
                    float axv[4] = {((const float*)&a0)[kc], ((const float*)&a1)[kc],
                                    ((const float*)&a2)[kc], ((const float*)&a3)[kc]};
                    #pragma unroll
                    for (int i = 0; i < 4; ++i) {
                        acc[i][0] = fmaf(axv[i], b0.x, acc[i][0]);
                        acc[i][1] = fmaf(axv[i], b0.y, acc[i][1]);
                        acc[i][2] = fmaf(axv[i], b0.z, acc[i][2]);
                        acc[i][3] = fmaf(axv[i], b0.w, acc[i][3]);
                        acc[i][4] = fmaf(axv[i], b1.x, acc[i][4]);
                        acc[i][5] = fmaf(axv[i], b1.y, acc[i][5]);
                        acc[i][6] = fmaf(axv[i], b1.z, acc[i][6]);
                        acc[i][7] = fmaf(axv[i], b1.w, acc[i][7]);
                    }
                }
            }
            __syncthreads();
        }

        #pragma unroll
        for (int j = 0; j < 8; ++j) {
            int k = cb0 + (j < 4 ? (tx*4 + j) : (64 + tx*4 + (j - 4)));
            float c2v = c2l[k];
            #pragma unroll
            for (int i = 0; i < 4; ++i) {
                float s = fmaf(-2.f, acc[i][j], c2v);
                if (s < bestv[i]) { bestv[i] = s; besti[i] = k; }
            }
        }
    }

    #pragma unroll
    for (int i = 0; i < 4; ++i) {
        red_s[(ty*4 + i) * 16 + tx] = bestv[i];
        red_i[(ty*4 + i) * 16 + tx] = besti[i];
    }
    __syncthreads();
    if (tid < MT) {
        float bv = red_s[tid * 16];
        int   bi = red_i[tid * 16];
        #pragma unroll
        for (int j = 1; j < 16; ++j) {
            float v  = red_s[tid * 16 + j];
            int   ii = red_i[tid * 16 + j];
            if (v < bv || (v == bv && ii < bi)) { bv = v; bi = ii; }
        }
        kbest[tid] = bi;
        idxout[(tok0 + tid) * NLV + lvl] = (float)bi;
    }
    __syncthreads();

    for (int e = tid; e < MT * (DM / 4); e += NTH) {
        int t = e >> 7, d4 = e & 127;
        size_t goff = (tok0 + t) * DM + d4 * 4;
        float4 r = *(const float4*)&rin[goff];
        float4 c = ((const float4*)(cbl + (size_t)kbest[t] * DM))[d4];
        r.x -= c.x; r.y -= c.y; r.z -= c.z; r.w -= c.w;
        if (is_last) {
            float4 xv = *(const float4*)&xin[goff];
            float4 q = make_float4(xv.x - r.x, xv.y - r.y, xv.z - r.z, xv.w - r.w);
            *(float4*)&rout[goff] = q;
        } else {
            *(float4*)&rout[goff] = r;
        }
    }
}

// =================== launch ===================
extern "C" void kernel_launch(void* const* d_in, const int* in_sizes, int n_in,
                              void* d_out, int out_size, void* d_ws, size_t ws_size,
                              hipStream_t stream) {
    const float* x   = (const float*)d_in[0];   // [8,4096,512]
    const float* cbs = (const float*)d_in[1];   // [8,1024,512]
    float* qout   = (float*)d_out;                       // [8,4096,512]
    float* idxout = qout + (size_t)NTOK * DM;            // [8,4096,8] as float

    const size_t B_ELE = (size_t)NLV * KCB * DM;   // 4,194,304
    const size_t A_ELE = (size_t)NTOK * DM;        // 16,777,216
    const size_t needed = 2 * B_ELE * sizeof(f16) + 2 * A_ELE * sizeof(f16)
                        + (size_t)NLV * KCB * sizeof(float);

    if (ws_size >= needed) {
        f16* Bhi = (f16*)d_ws;
        f16* Blo = Bhi + B_ELE;
        f16* Ahi = Blo + B_ELE;
        f16* Alo = Ahi + A_ELE;
        float* c2 = (float*)(Alo + A_ELE);

        split_kernel<<<(int)(B_ELE / 4 / 256), 256, 0, stream>>>(cbs, Bhi, Blo);
        split_kernel<<<(int)(A_ELE / 4 / 256), 256, 0, stream>>>(x, Ahi, Alo);
        c2_kernel<<<NLV * KCB, 64, 0, stream>>>(cbs, c2);

        const int nblocks = NTOK / MB;  // 512
        for (int l = 0; l < NLV; ++l) {
            const float* rin = (l == 0) ? x : qout;
            rvq_mfma<<<nblocks, 256, 0, stream>>>(rin, qout, x, cbs,
                                                  Bhi, Blo, Ahi, Alo, c2, idxout,
                                                  l, (l == NLV - 1) ? 1 : 0);
        }
    } else {
        float* c2 = (float*)d_ws;
        c2_kernel<<<NLV * KCB, 64, 0, stream>>>(cbs, c2);
        const int nblocks = NTOK / MT;
        for (int l = 0; l < NLV; ++l) {
            const float* rin = (l == 0) ? x : qout;
            rvq_level_fb<<<nblocks, NTH, 0, stream>>>(rin, qout, x, cbs, c2, idxout,
                                                      l, (l == NLV - 1) ? 1 : 0);
        }
    }
}

// Round 3
// 1151.716 us; speedup vs baseline: 3.6368x; 1.0990x over previous
//
#include <hip/hip_runtime.h>
#include <stdint.h>

#define NLV 8
#define KCB 1024
#define DM  512
#define NTOK (8*4096)

typedef _Float16 f16;
typedef f16  f16x4 __attribute__((ext_vector_type(4)));
typedef f16  f16x8 __attribute__((ext_vector_type(8)));
typedef float f32x4 __attribute__((ext_vector_type(4)));

#define SPLIT_SCALE 2048.0f
#define INV_SPLIT   (1.0f/2048.0f)

// async global->LDS: HW writes wave-uniform base + lane*16
typedef __attribute__((address_space(1))) const unsigned int* as1p;
typedef __attribute__((address_space(3))) unsigned int*       as3p;
__device__ __forceinline__ void gll16(const void* g, void* l) {
    __builtin_amdgcn_global_load_lds((as1p)g, (as3p)l, 16, 0, 0);
}

// ---------------- c2 precompute ----------------
__global__ void c2_kernel(const float* __restrict__ cbs, float* __restrict__ c2) {
    int row  = blockIdx.x;
    int lane = threadIdx.x;
    const float4* p4 = (const float4*)(cbs + (size_t)row * DM);
    float4 a = p4[lane];
    float4 b = p4[lane + 64];
    float s = a.x*a.x + a.y*a.y + a.z*a.z + a.w*a.w
            + b.x*b.x + b.y*b.y + b.z*b.z + b.w*b.w;
    #pragma unroll
    for (int off = 32; off > 0; off >>= 1) s += __shfl_down(s, off, 64);
    if (lane == 0) c2[row] = s;
}

// ---------------- hi/lo split ----------------
__global__ void split_kernel(const float* __restrict__ src,
                             f16* __restrict__ hi, f16* __restrict__ lo) {
    size_t i = (size_t)blockIdx.x * 256 + threadIdx.x;   // float4 index
    float4 v = ((const float4*)src)[i];
    f16x4 h, l;
    h.x = (f16)v.x; l.x = (f16)((v.x - (float)h.x) * SPLIT_SCALE);
    h.y = (f16)v.y; l.y = (f16)((v.y - (float)h.y) * SPLIT_SCALE);
    h.z = (f16)v.z; l.z = (f16)((v.z - (float)h.z) * SPLIT_SCALE);
    h.w = (f16)v.w; l.w = (f16)((v.w - (float)h.w) * SPLIT_SCALE);
    ((f16x4*)hi)[i] = h;
    ((f16x4*)lo)[i] = l;
}

// ---------------- main MFMA level kernel ----------------
// 512 threads = 8 waves (2 M-strips x 4 N-strips of 64x64 wave tiles).
// M=128 tokens/block, N chunk = 256, KS=32. Double-buffered LDS (2 x 48 KB),
// ONE barrier per kstep with cross-buffer global_load_lds prefetch.
// LDS granule swizzle: element granule q of row n stored at slot q^((n>>1)&3)
// -> all b128 frag reads are 2-way bank aliased (free).
#define MB   128
#define NCH  256
#define KS   32
#define NTHR 512
#define BUFB 49152   // bytes per LDS buffer: Ah 8K | Al 8K | Bh 16K | Bl 16K

__global__ __launch_bounds__(NTHR, 2)
void rvq_mfma(const float* __restrict__ xin, float* __restrict__ qout,
              const float* __restrict__ cbs,
              const f16* __restrict__ Bhi, const f16* __restrict__ Blo,
              f16* __restrict__ Ahi, f16* __restrict__ Alo,
              const float* __restrict__ c2g, float* __restrict__ idxout,
              int lvl, int is_last)
{
    __shared__ char smem[2 * BUFB];
    const int tid  = threadIdx.x;
    const int lane = tid & 63;
    const int wid  = tid >> 6;       // 0..7
    const int wm   = wid >> 2;       // 0..1  M strip
    const int wn   = wid & 3;        // 0..3  N strip
    const int tx   = lane & 15;
    const int q    = lane >> 4;
    const size_t tok0 = (size_t)blockIdx.x * MB;

    const f16*   Bh_l = Bhi + (size_t)lvl * KCB * DM;
    const f16*   Bl_l = Blo + (size_t)lvl * KCB * DM;
    const float* c2l  = c2g + lvl * KCB;
    const float* cbl  = cbs + (size_t)lvl * KCB * DM;

    // staging: thread tid fills LDS slot tid (A) / tid,tid+512 (B); slot s of a
    // plane holds row n=s>>2, granule-position s&3, actual granule g = (s&3)^((n>>1)&3)
    const int stg  = (tid & 3) ^ ((tid >> 3) & 3);   // granule to fetch
    const int srow = tid >> 2;                       // 0..127
    const int rsw  = q ^ ((tx >> 1) & 3);            // read-side granule position

    auto stage = [&](char* bb, int cb0, int k0) {
        const int ko = k0 + stg * 8;
        const size_t arow = (tok0 + srow) * (size_t)DM + ko;
        gll16(&Ahi[arow], bb +     0 + wid * 1024);
        gll16(&Alo[arow], bb +  8192 + wid * 1024);
        const size_t br0 = (size_t)(cb0 + srow)       * DM + ko;
        const size_t br1 = (size_t)(cb0 + 128 + srow) * DM + ko;
        gll16(&Bh_l[br0], bb + 16384        + wid * 1024);
        gll16(&Bh_l[br1], bb + 16384 + 8192 + wid * 1024);
        gll16(&Bl_l[br0], bb + 32768        + wid * 1024);
        gll16(&Bl_l[br1], bb + 32768 + 8192 + wid * 1024);
    };

    float bestv[16];
    int   besti[16];
    #pragma unroll
    for (int t = 0; t < 16; ++t) { bestv[t] = 3.4e38f; besti[t] = 0; }

    stage(smem, 0, 0);   // ch=0, kk=0 -> buf0

    for (int ch = 0; ch < KCB / NCH; ++ch) {
        const int cb0 = ch * NCH;
        f32x4 ahh[4][4], axx[4][4];
        #pragma unroll
        for (int i = 0; i < 4; ++i)
            #pragma unroll
            for (int j = 0; j < 4; ++j) { ahh[i][j] = (f32x4)0.0f; axx[i][j] = (f32x4)0.0f; }

        for (int kk = 0; kk < DM / KS; ++kk) {
            char* bb  = smem + (kk & 1) * BUFB;
            char* bbn = smem + ((kk & 1) ^ 1) * BUFB;
            __syncthreads();                 // drains prefetch issued ~1 MFMA phase ago
            if (kk < DM / KS - 1)      stage(bbn, cb0, (kk + 1) * KS);
            else if (ch < KCB/NCH - 1) stage(bbn, cb0 + NCH, 0);

            const f16* sAh = (const f16*)(bb);
            const f16* sAl = (const f16*)(bb + 8192);
            const f16* sBh = (const f16*)(bb + 16384);
            const f16* sBl = (const f16*)(bb + 32768);

            f16x8 ah[4], al[4];
            #pragma unroll
            for (int i = 0; i < 4; ++i) {
                int off = (wm * 64 + i * 16 + tx) * 32 + rsw * 8;
                ah[i] = *(const f16x8*)&sAh[off];
                al[i] = *(const f16x8*)&sAl[off];
            }
            #pragma unroll
            for (int j = 0; j < 4; ++j) {
                int boff = (wn * 64 + j * 16 + tx) * 32 + rsw * 8;
                f16x8 bh = *(const f16x8*)&sBh[boff];
                f16x8 bl = *(const f16x8*)&sBl[boff];
                #pragma unroll
                for (int i = 0; i < 4; ++i) {
                    ahh[i][j] = __builtin_amdgcn_mfma_f32_16x16x32_f16(ah[i], bh, ahh[i][j], 0, 0, 0);
                    axx[i][j] = __builtin_amdgcn_mfma_f32_16x16x32_f16(ah[i], bl, axx[i][j], 0, 0, 0);
                    axx[i][j] = __builtin_amdgcn_mfma_f32_16x16x32_f16(al[i], bh, axx[i][j], 0, 0, 0);
                }
            }
        }

        // chunk argmin epilogue (C/D: col=lane&15, row=(lane>>4)*4+reg)
        #pragma unroll
        for (int j = 0; j < 4; ++j) {
            int n = cb0 + wn * 64 + j * 16 + tx;
            float c2v = c2l[n];
            #pragma unroll
            for (int i = 0; i < 4; ++i)
                #pragma unroll
                for (int r = 0; r < 4; ++r) {
                    float dot = ahh[i][j][r] + axx[i][j][r] * INV_SPLIT;
                    float s = fmaf(-2.f, dot, c2v);
                    int t = i * 4 + r;
                    if (s < bestv[t]) { bestv[t] = s; besti[t] = n; }
                }
        }
    }

    // cross-lane argmin over tx (lanes with same q hold same m rows)
    #pragma unroll
    for (int t = 0; t < 16; ++t) {
        float v = bestv[t]; int bi = besti[t];
        #pragma unroll
        for (int off = 1; off < 16; off <<= 1) {
            float ov = __shfl_xor(v, off, 64);
            int   oi = __shfl_xor(bi, off, 64);
            if (ov < v || (ov == v && oi < bi)) { v = ov; bi = oi; }
        }
        bestv[t] = v; besti[t] = bi;
    }

    // cross-wave reduce over wn (4 waves per M strip); overlay on buf0 (safe:
    // last buf0 frag reads were kstep 14, all retired before the barriers below)
    float* redV = (float*)smem;            // [2 wm][4 wn][64 m]  2 KB
    int*   redI = (int*)(smem + 2048);     // 2 KB
    int*   kbst = (int*)(smem + 4096);     // 128 ints
    __syncthreads();
    if (tx == 0) {
        #pragma unroll
        for (int i = 0; i < 4; ++i)
            #pragma unroll
            for (int r = 0; r < 4; ++r) {
                int m = i * 16 + q * 4 + r;
                redV[(wm * 4 + wn) * 64 + m] = bestv[i * 4 + r];
                redI[(wm * 4 + wn) * 64 + m] = besti[i * 4 + r];
            }
    }
    __syncthreads();
    if (tid < MB) {
        int mwm = tid >> 6, m = tid & 63;
        float bv = redV[(mwm * 4) * 64 + m];
        int   bi = redI[(mwm * 4) * 64 + m];
        #pragma unroll
        for (int w = 1; w < 4; ++w) {
            float v  = redV[(mwm * 4 + w) * 64 + m];
            int   ii = redI[(mwm * 4 + w) * 64 + m];
            if (v < bv || (v == bv && ii < bi)) { bv = v; bi = ii; }
        }
        kbst[tid] = bi;
        idxout[(tok0 + tid) * NLV + lvl] = (float)bi;
    }
    __syncthreads();

    // residual update on the hi/lo planes (fp32 compute, ~2^-22 reconstruction
    // error per level -- far below argmin margins). Last level writes q = x - r.
    for (int it = 0; it < 16; ++it) {
        int e  = it * NTHR + tid;          // 128 tok x 64 granules of 8
        int t  = e >> 6, d8 = e & 63;
        size_t go = (tok0 + t) * (size_t)DM + d8 * 8;
        f16x8 h8 = *(const f16x8*)&Ahi[go];
        f16x8 l8 = *(const f16x8*)&Alo[go];
        const float* cp = &cbl[(size_t)kbst[t] * DM + d8 * 8];
        float4 c0 = *(const float4*)cp;
        float4 c1 = *(const float4*)(cp + 4);
        float r[8];
        r[0] = (float)h8[0] + (float)l8[0] * INV_SPLIT - c0.x;
        r[1] = (float)h8[1] + (float)l8[1] * INV_SPLIT - c0.y;
        r[2] = (float)h8[2] + (float)l8[2] * INV_SPLIT - c0.z;
        r[3] = (float)h8[3] + (float)l8[3] * INV_SPLIT - c0.w;
        r[4] = (float)h8[4] + (float)l8[4] * INV_SPLIT - c1.x;
        r[5] = (float)h8[5] + (float)l8[5] * INV_SPLIT - c1.y;
        r[6] = (float)h8[6] + (float)l8[6] * INV_SPLIT - c1.z;
        r[7] = (float)h8[7] + (float)l8[7] * INV_SPLIT - c1.w;
        if (is_last) {
            float4 x0 = *(const float4*)&xin[go];
            float4 x1 = *(const float4*)&xin[go + 4];
            float4 q0 = make_float4(x0.x - r[0], x0.y - r[1], x0.z - r[2], x0.w - r[3]);
            float4 q1 = make_float4(x1.x - r[4], x1.y - r[5], x1.z - r[6], x1.w - r[7]);
            *(float4*)&qout[go]     = q0;
            *(float4*)&qout[go + 4] = q1;
        } else {
            f16x8 h, l;
            #pragma unroll
            for (int k = 0; k < 8; ++k) {
                h[k] = (f16)r[k];
                l[k] = (f16)((r[k] - (float)h[k]) * SPLIT_SCALE);
            }
            *(f16x8*)&Ahi[go] = h;
            *(f16x8*)&Alo[go] = l;
        }
    }
}

// =================== launch ===================
extern "C" void kernel_launch(void* const* d_in, const int* in_sizes, int n_in,
                              void* d_out, int out_size, void* d_ws, size_t ws_size,
                              hipStream_t stream) {
    const float* x   = (const float*)d_in[0];   // [8,4096,512]
    const float* cbs = (const float*)d_in[1];   // [8,1024,512]
    float* qout   = (float*)d_out;                       // [8,4096,512]
    float* idxout = qout + (size_t)NTOK * DM;            // [8,4096,8] as float

    const size_t B_ELE = (size_t)NLV * KCB * DM;   // 4,194,304
    const size_t A_ELE = (size_t)NTOK * DM;        // 16,777,216

    f16* Bhi = (f16*)d_ws;
    f16* Blo = Bhi + B_ELE;
    f16* Ahi = Blo + B_ELE;
    f16* Alo = Ahi + A_ELE;
    float* c2 = (float*)(Alo + A_ELE);

    split_kernel<<<(int)(B_ELE / 4 / 256), 256, 0, stream>>>(cbs, Bhi, Blo);
    split_kernel<<<(int)(A_ELE / 4 / 256), 256, 0, stream>>>(x, Ahi, Alo);
    c2_kernel<<<NLV * KCB, 64, 0, stream>>>(cbs, c2);

    const int nblocks = NTOK / MB;  // 256
    for (int l = 0; l < NLV; ++l) {
        rvq_mfma<<<nblocks, NTHR, 0, stream>>>(x, qout, cbs,
                                               Bhi, Blo, Ahi, Alo, c2, idxout,
                                               l, (l == NLV - 1) ? 1 : 0);
    }
}